// Round 18
// baseline (7107.819 us; speedup 1.0000x reference)
//
#include <hip/hip_runtime.h>
#include <hip/hip_bf16.h>
#include <hip/hip_cooperative_groups.h>

namespace cg = cooperative_groups;

typedef short short8 __attribute__((ext_vector_type(8)));
typedef float f32x4 __attribute__((ext_vector_type(4)));

#define BROWS 64
#define NTHR  512
#define XK    96
#define XSTR  104
#define HSTR  264
#define HIDSTR 129
#define NKT0  11
#define NKT1  16
#define NKTO  8
#define PK0_ELEMS (64*NKT0*512)
#define PK1_ELEMS (64*NKT1*512)
#define PKO_ELEMS (8*NKTO*512)

// LDS layout (bytes) — 149,264 B, STATIC
#define L_X    0
#define L_H    13312
#define HBUF   (BROWS*HSTR)
#define HBUF_B (HBUF*2)
#define L_HID  (L_H + 3*HBUF_B)      // 114688 : [64][129] f32
#define L_OW2  (L_HID + BROWS*HIDSTR*4) // 147712
#define L_OB2  (L_OW2 + 1536)        // 149248
#define LDS_TOTAL 149264

__device__ inline unsigned short f2bf(float x){
  unsigned u = __float_as_uint(x);
  u += 0x7FFFu + ((u >> 16) & 1u);
  return (unsigned short)(u >> 16);
}
__device__ inline float bf2f(unsigned short s){ return __uint_as_float(((unsigned)s) << 16); }
__device__ inline float sigm(float x){ return 1.f / (1.f + __expf(-x)); }
__device__ inline float ftanh(float x){ float e = __expf(2.f*x); return 1.f - 2.f/(e + 1.f); }

// ---------------- weight pre-pack (identical to R13) ----------------
__global__ void pack_weights(const float* __restrict__ wih0, const float* __restrict__ whh0,
                             const float* __restrict__ bih0, const float* __restrict__ bhh0,
                             const float* __restrict__ wih1, const float* __restrict__ whh1,
                             const float* __restrict__ ow1,
                             unsigned short* __restrict__ wsb){
  int idx = blockIdx.x * blockDim.x + threadIdx.x;
  int total = PK0_ELEMS + PK1_ELEMS + PKO_ELEMS;
  if (idx >= total) return;
  float w;
  size_t off;
  if (idx < PK0_ELEMS) {
    int nt = idx / (NKT0*512), rem = idx % (NKT0*512), kt = rem / 512, li = rem % 512;
    int lane = li >> 3, j = li & 7;
    int n = lane & 15, k = ((lane >> 4) << 3) + j;
    int Kg = kt*32 + k, g = nt*16 + n;
    if (Kg < 73)        w = wih0[g*73 + Kg];
    else if (Kg == 73)  w = bih0[g] + bhh0[g];
    else if (Kg < XK)   w = 0.f;
    else                w = whh0[g*256 + (Kg - XK)];
    off = ((size_t)(nt*NKT0 + kt)*64 + lane)*8 + j;
  } else if (idx < PK0_ELEMS + PK1_ELEMS) {
    int i2 = idx - PK0_ELEMS;
    int nt = i2 / (NKT1*512), rem = i2 % (NKT1*512), kt = rem / 512, li = rem % 512;
    int lane = li >> 3, j = li & 7;
    int n = lane & 15, k = ((lane >> 4) << 3) + j;
    int Kg = kt*32 + k, g = nt*16 + n;
    w = (Kg < 256) ? wih1[g*256 + Kg] : whh1[g*256 + (Kg - 256)];
    off = (size_t)PK0_ELEMS + ((size_t)(nt*NKT1 + kt)*64 + lane)*8 + j;
  } else {
    int i2 = idx - PK0_ELEMS - PK1_ELEMS;
    int nt = i2 / (NKTO*512), rem = i2 % (NKTO*512), kt = rem / 512, li = rem % 512;
    int lane = li >> 3, j = li & 7;
    int n = lane & 15, k = ((lane >> 4) << 3) + j;
    int Kg = kt*32 + k, uh = nt*16 + n;
    w = ow1[uh*256 + Kg];
    off = (size_t)PK0_ELEMS + (size_t)PK1_ELEMS + ((size_t)(nt*NKTO + kt)*64 + lane)*8 + j;
  }
  wsb[off] = f2bf(w);
}

// ---------------- persistent rollout kernel ----------------
// == R13 (best, 5721us) + ONE change: cooperative launch with grid.sync() per
// timestep. Model from 17 rounds: time ~= FETCH / 2.1 TB/s (concurrency-bound
// L2-miss path: ~4 loads in flight/wave x 8 waves = 32 lines/CU x ~600cy L3).
// FETCH = demand(22.5GB, register-cap-bound) x miss(~50%). The miss on a 1.76MB
// L2-resident stream is inter-block DRIFT: 32 blocks/XCD spread over >1 step of
// stream distance -> cyclic working set > 4MB L2 -> thrash. grid.sync() each
// step bounds drift to <1 step (<=3.5MB ~ L2 capacity).
__global__ void __launch_bounds__(NTHR)
traj_main(const float* __restrict__ z, const float* __restrict__ cond,
          const float* __restrict__ fiw, const float* __restrict__ fib,
          const float* __restrict__ bih1, const float* __restrict__ bhh1,
          const float* __restrict__ ob1,  const float* __restrict__ ow2,
          const float* __restrict__ ob2,
          const unsigned short* __restrict__ wsb, const int* __restrict__ seqp,
          float* __restrict__ out){
  __shared__ __align__(16) char smem[LDS_TOTAL];
  unsigned short* Xl  = (unsigned short*)(smem + L_X);
  unsigned short* Hl  = (unsigned short*)(smem + L_H);
  float*          HIDl= (float*)(smem + L_HID);
  float*          OW2l= (float*)(smem + L_OW2);
  float*          OB2l= (float*)(smem + L_OB2);

  cg::grid_group grid = cg::this_grid();

  const int tid = threadIdx.x, wv = tid >> 6, lane = tid & 63;
  const int bid = blockIdx.x;
  const int row0 = bid * BROWS;
  const int T = *seqp;

  const unsigned short* pk0i = wsb;
  const unsigned short* pk1i = wsb + (size_t)PK0_ELEMS;
  const unsigned short* pkoi = wsb + (size_t)PK0_ELEMS + (size_t)PK1_ELEMS;

  {
    int r = tid >> 3, seg = tid & 7;
    int gr = row0 + r;
    for (int c = seg*13; c < seg*13 + 13; ++c) {
      float v;
      if (c < 3)        v = cond[gr*6 + c];
      else if (c < 67)  v = z[gr*64 + (c - 3)];
      else if (c < 73)  v = cond[gr*6 + (c - 67)];
      else if (c == 73) v = 1.0f;
      else              v = 0.f;
      Xl[r*XSTR + c] = f2bf(v);
    }
  }
  if (tid < 384) OW2l[tid] = ow2[tid];
  if (tid < 3)   OB2l[tid] = ob2[tid];

  {
    int r = tid >> 3, ub = (tid & 7) * 32;
    int gr = row0 + r;
    #pragma unroll 1
    for (int u = ub; u < ub + 32; ++u) {
      float s0 = fib[u], s1 = fib[256 + u];
      const float* w0r = fiw + (size_t)u * 70;
      const float* w1r = fiw + (size_t)(256 + u) * 70;
      for (int jj = 0; jj < 64; ++jj) { float xv = z[gr*64 + jj]; s0 += xv * w0r[jj]; s1 += xv * w1r[jj]; }
      for (int jj = 0; jj < 6;  ++jj) { float xv = cond[gr*6 + jj]; s0 += xv * w0r[64 + jj]; s1 += xv * w1r[64 + jj]; }
      Hl[0*HBUF + r*HSTR + u] = f2bf(s0);
      Hl[1*HBUF + r*HSTR + u] = f2bf(s1);
    }
  }

  float bias1r[8];
  #pragma unroll
  for (int p = 0; p < 2; ++p) {
    int u = wv*32 + p*16 + (lane & 15);
    #pragma unroll
    for (int g = 0; g < 4; ++g)
      bias1r[p*4 + g] = bih1[g*256 + u] + bhh1[g*256 + u];
  }
  float ob1r = ob1[wv*16 + (lane & 15)];

  float c0s[32], c1s[32];
  #pragma unroll
  for (int i = 0; i < 32; ++i) { c0s[i] = 0.f; c1s[i] = 0.f; }

  __syncthreads();

  const int arow = lane & 15, koff = (lane >> 4) * 8;

  int ia = 0, ib = 1, ic = 2;

  for (int t = 0; t < T; ++t) {
    if (t) grid.sync();   // bound inter-block drift to <1 step of weight-stream distance

    const unsigned short* Ha = Hl + ia*HBUF;
    const unsigned short* Hb = Hl + ib*HBUF;
    unsigned short*       Hc = Hl + ic*HBUF;
    unsigned short*       HaW= Hl + ia*HBUF;

    // ===== M1: gates0 (bias in X col 73); h0n -> H[ic] =====
    #pragma unroll
    for (int p = 0; p < 2; ++p) {
      const unsigned short* wb = pk0i + ((size_t)((wv*2 + p)*NKT0)*64 + lane)*8;

      short8 wh[2][4];
      #pragma unroll
      for (int g = 0; g < 4; ++g)
        wh[0][g] = *(const short8*)(wb + (size_t)g*(16*NKT0*512));

      f32x4 acc[4][4];
      #pragma unroll
      for (int mt = 0; mt < 4; ++mt)
        #pragma unroll
        for (int g = 0; g < 4; ++g) acc[mt][g] = (f32x4){0.f, 0.f, 0.f, 0.f};

      #pragma unroll
      for (int kt = 0; kt < NKT0; ++kt) {
        const int cb = kt & 1, nb = cb ^ 1;
        if (kt + 1 < NKT0) {
          #pragma unroll
          for (int g = 0; g < 4; ++g)
            wh[nb][g] = *(const short8*)(wb + (size_t)g*(16*NKT0*512) + (size_t)(kt+1)*512);
        }
        short8 a[4];
        if (kt < 3) {
          #pragma unroll
          for (int mt = 0; mt < 4; ++mt)
            a[mt] = *(const short8*)(Xl + (mt*16 + arow)*XSTR + kt*32 + koff);
        } else {
          #pragma unroll
          for (int mt = 0; mt < 4; ++mt)
            a[mt] = *(const short8*)(Ha + (mt*16 + arow)*HSTR + (kt - 3)*32 + koff);
        }
        #pragma unroll
        for (int g = 0; g < 4; ++g)
          #pragma unroll
          for (int mt = 0; mt < 4; ++mt)
            acc[mt][g] = __builtin_amdgcn_mfma_f32_16x16x32_bf16(a[mt], wh[cb][g], acc[mt][g], 0, 0, 0);
      }

      const int u = wv*32 + p*16 + (lane & 15);
      #pragma unroll
      for (int mt = 0; mt < 4; ++mt) {
        #pragma unroll
        for (int q = 0; q < 4; ++q) {
          float iv = sigm(acc[mt][0][q]);
          float fv = sigm(acc[mt][1][q]);
          float gv = ftanh(acc[mt][2][q]);
          float ov = sigm(acc[mt][3][q]);
          float cn = fv * c0s[(p*4 + mt)*4 + q] + iv * gv;
          c0s[(p*4 + mt)*4 + q] = cn;
          float hn = ov * ftanh(cn);
          int r = mt*16 + ((lane >> 4) << 2) + q;
          Hc[r*HSTR + u] = f2bf(hn);
        }
      }
    }
    __syncthreads();  // B1

    // ===== M2: gates1 (+b); h1n -> H[ia] =====
    #pragma unroll
    for (int p = 0; p < 2; ++p) {
      const unsigned short* wb = pk1i + ((size_t)((wv*2 + p)*NKT1)*64 + lane)*8;

      short8 wh[2][4];
      #pragma unroll
      for (int g = 0; g < 4; ++g)
        wh[0][g] = *(const short8*)(wb + (size_t)g*(16*NKT1*512));

      f32x4 acc[4][4];
      #pragma unroll
      for (int mt = 0; mt < 4; ++mt)
        #pragma unroll
        for (int g = 0; g < 4; ++g) {
          float b = bias1r[p*4 + g];
          acc[mt][g] = (f32x4){b, b, b, b};
        }

      #pragma unroll
      for (int kt = 0; kt < NKT1; ++kt) {
        const int cb = kt & 1, nb = cb ^ 1;
        if (kt + 1 < NKT1) {
          #pragma unroll
          for (int g = 0; g < 4; ++g)
            wh[nb][g] = *(const short8*)(wb + (size_t)g*(16*NKT1*512) + (size_t)(kt+1)*512);
        }
        short8 a[4];
        if (kt < 8) {
          #pragma unroll
          for (int mt = 0; mt < 4; ++mt)
            a[mt] = *(const short8*)(Hc + (mt*16 + arow)*HSTR + kt*32 + koff);
        } else {
          #pragma unroll
          for (int mt = 0; mt < 4; ++mt)
            a[mt] = *(const short8*)(Hb + (mt*16 + arow)*HSTR + (kt - 8)*32 + koff);
        }
        #pragma unroll
        for (int g = 0; g < 4; ++g)
          #pragma unroll
          for (int mt = 0; mt < 4; ++mt)
            acc[mt][g] = __builtin_amdgcn_mfma_f32_16x16x32_bf16(a[mt], wh[cb][g], acc[mt][g], 0, 0, 0);
      }

      const int u = wv*32 + p*16 + (lane & 15);
      #pragma unroll
      for (int mt = 0; mt < 4; ++mt) {
        #pragma unroll
        for (int q = 0; q < 4; ++q) {
          float iv = sigm(acc[mt][0][q]);
          float fv = sigm(acc[mt][1][q]);
          float gv = ftanh(acc[mt][2][q]);
          float ov = sigm(acc[mt][3][q]);
          float cn = fv * c1s[(p*4 + mt)*4 + q] + iv * gv;
          c1s[(p*4 + mt)*4 + q] = cn;
          float hn = ov * ftanh(cn);
          int r = mt*16 + ((lane >> 4) << 2) + q;
          HaW[r*HSTR + u] = f2bf(hn);
        }
      }
    }
    __syncthreads();  // B2

    // ===== M3: hid = relu(h1n @ out_w1^T + ob1) -> LDS fp32 =====
    {
      const unsigned short* wb = pkoi + ((size_t)(wv*NKTO)*64 + lane)*8;
      short8 wh[2];
      wh[0] = *(const short8*)(wb);

      f32x4 acc3[4];
      #pragma unroll
      for (int mt = 0; mt < 4; ++mt) acc3[mt] = (f32x4){ob1r, ob1r, ob1r, ob1r};

      #pragma unroll
      for (int kt = 0; kt < NKTO; ++kt) {
        const int cb = kt & 1, nb = cb ^ 1;
        if (kt + 1 < NKTO)
          wh[nb] = *(const short8*)(wb + (size_t)(kt+1)*512);
        short8 a[4];
        #pragma unroll
        for (int mt = 0; mt < 4; ++mt)
          a[mt] = *(const short8*)(HaW + (mt*16 + arow)*HSTR + kt*32 + koff);
        #pragma unroll
        for (int mt = 0; mt < 4; ++mt)
          acc3[mt] = __builtin_amdgcn_mfma_f32_16x16x32_bf16(a[mt], wh[cb], acc3[mt], 0, 0, 0);
      }
      const int uh = wv*16 + (lane & 15);
      #pragma unroll
      for (int mt = 0; mt < 4; ++mt)
        #pragma unroll
        for (int q = 0; q < 4; ++q) {
          float hv = fmaxf(acc3[mt][q], 0.f);
          int r = mt*16 + ((lane >> 4) << 2) + q;
          HIDl[r*HIDSTR + uh] = hv;
        }
    }
    __syncthreads();  // B3

    // ===== M4: out = hid @ out_w2^T + ob2 =====
    {
      int r = tid >> 3, e = tid & 7;
      const float* hrow = HIDl + r*HIDSTR + e*16;
      float s0 = 0.f, s1 = 0.f, s2 = 0.f;
      #pragma unroll
      for (int k = 0; k < 16; ++k) {
        float hv = hrow[k];
        int kk = e*16 + k;
        s0 += hv * OW2l[kk];
        s1 += hv * OW2l[128 + kk];
        s2 += hv * OW2l[256 + kk];
      }
      #pragma unroll
      for (int d = 4; d; d >>= 1) {
        s0 += __shfl_down(s0, d, 8);
        s1 += __shfl_down(s1, d, 8);
        s2 += __shfl_down(s2, d, 8);
      }
      if (e == 0) {
        s0 += OB2l[0]; s1 += OB2l[1]; s2 += OB2l[2];
        int gr = row0 + r;
        float* orow = out + (size_t)gr * (T*3) + t*3;
        orow[0] = s0; orow[1] = s1; orow[2] = s2;
        Xl[r*XSTR + 0] = f2bf(s0);
        Xl[r*XSTR + 1] = f2bf(s1);
        Xl[r*XSTR + 2] = f2bf(s2);
      }
    }
    __syncthreads();  // B4

    int tmp = ia; ia = ic; ic = ib; ib = tmp;
  }
}

extern "C" void kernel_launch(void* const* d_in, const int* in_sizes, int n_in,
                              void* d_out, int out_size, void* d_ws, size_t ws_size,
                              hipStream_t stream){
  const float* z    = (const float*)d_in[0];
  const float* cond = (const float*)d_in[1];
  const float* fiw  = (const float*)d_in[2];
  const float* fib  = (const float*)d_in[3];
  const float* wih0 = (const float*)d_in[4];
  const float* whh0 = (const float*)d_in[5];
  const float* bih0 = (const float*)d_in[6];
  const float* bhh0 = (const float*)d_in[7];
  const float* wih1 = (const float*)d_in[8];
  const float* whh1 = (const float*)d_in[9];
  const float* bih1 = (const float*)d_in[10];
  const float* bhh1 = (const float*)d_in[11];
  const float* ow1  = (const float*)d_in[12];
  const float* ob1  = (const float*)d_in[13];
  const float* ow2  = (const float*)d_in[14];
  const float* ob2  = (const float*)d_in[15];
  const int*   seqp = (const int*)d_in[16];
  unsigned short* wsb = (unsigned short*)d_ws;
  float* outp = (float*)d_out;

  int packtot = PK0_ELEMS + PK1_ELEMS + PKO_ELEMS;
  pack_weights<<<(packtot + 255)/256, 256, 0, stream>>>(wih0, whh0, bih0, bhh0,
                                                        wih1, whh1, ow1, wsb);

  void* args[] = {(void*)&z, (void*)&cond, (void*)&fiw, (void*)&fib,
                  (void*)&bih1, (void*)&bhh1, (void*)&ob1, (void*)&ow2,
                  (void*)&ob2, (void*)&wsb, (void*)&seqp, (void*)&outp};
  hipLaunchCooperativeKernel((void*)traj_main, dim3(16384/BROWS), dim3(NTHR),
                             args, 0, stream);
}

// Round 19
// 6542.311 us; speedup vs baseline: 1.0864x; 1.0864x over previous
//
#include <hip/hip_runtime.h>
#include <hip/hip_bf16.h>

typedef short short8 __attribute__((ext_vector_type(8)));
typedef float f32x4 __attribute__((ext_vector_type(4)));

#define BROWS 64
#define NTHR  512
#define XK    96
#define XSTR  104
#define HSTR  264
#define HID2STR 136
#define NKT0  11
#define NKT1  16
#define NKTO  8
#define PK0_ELEMS (64*NKT0*512)
#define PK1_ELEMS (64*NKT1*512)
#define PKO_ELEMS (8*NKTO*512)

// LDS layout (bytes) — 157,200 B STATIC
#define L_X    0
#define L_H    13312
#define HBUF   (BROWS*HSTR)              // 16896 ushorts per H buffer
#define HBUF_B (HBUF*2)                  // 33792 B
#define L_OW2  (L_H + 3*HBUF_B)          // 114688 : [3][128] f32
#define L_OB2  (L_OW2 + 1536)            // 116224
#define L_RING (L_OB2 + 16)              // 116240 : 8 waves x 5 slots x 1KB
#define LDS_TOTAL (L_RING + 8*5*1024)    // 157200
// HID ([64][136] bf16, 17408B) overlays the DEAD H buffer (h1(t)) during M3/M4.

#define WAITVM(N) { constexpr int _n=(N); \
  if constexpr(_n<=0)      asm volatile("s_waitcnt vmcnt(0)":::"memory"); \
  else if constexpr(_n==1) asm volatile("s_waitcnt vmcnt(1)":::"memory"); \
  else if constexpr(_n==2) asm volatile("s_waitcnt vmcnt(2)":::"memory"); \
  else                     asm volatile("s_waitcnt vmcnt(3)":::"memory"); }
#define LGKM0 asm volatile("s_waitcnt lgkmcnt(0)":::"memory")

__device__ inline unsigned short f2bf(float x){
  unsigned u = __float_as_uint(x);
  u += 0x7FFFu + ((u >> 16) & 1u);
  return (unsigned short)(u >> 16);
}
__device__ inline float bf2f(unsigned short s){ return __uint_as_float(((unsigned)s) << 16); }
__device__ inline float sigm(float x){ return 1.f / (1.f + __expf(-x)); }
__device__ inline float ftanh(float x){ float e = __expf(2.f*x); return 1.f - 2.f/(e + 1.f); }

// one 1KB weight tile: per-lane global src (base+lane*16B), wave-uniform LDS dst.
// HW writes dst + lane*16 -> exactly the packed consumption layout. Zero VGPR cost.
__device__ __forceinline__ void stage16(const unsigned short* g, unsigned short* l){
  __builtin_amdgcn_global_load_lds(
      (const __attribute__((address_space(1))) unsigned int*)g,
      (__attribute__((address_space(3))) unsigned int*)l, 16, 0, 0);
}

// ---------------- weight pre-pack (identical to R13) ----------------
__global__ void pack_weights(const float* __restrict__ wih0, const float* __restrict__ whh0,
                             const float* __restrict__ bih0, const float* __restrict__ bhh0,
                             const float* __restrict__ wih1, const float* __restrict__ whh1,
                             const float* __restrict__ ow1,
                             unsigned short* __restrict__ wsb){
  int idx = blockIdx.x * blockDim.x + threadIdx.x;
  int total = PK0_ELEMS + PK1_ELEMS + PKO_ELEMS;
  if (idx >= total) return;
  float w;
  size_t off;
  if (idx < PK0_ELEMS) {
    int nt = idx / (NKT0*512), rem = idx % (NKT0*512), kt = rem / 512, li = rem % 512;
    int lane = li >> 3, j = li & 7;
    int n = lane & 15, k = ((lane >> 4) << 3) + j;
    int Kg = kt*32 + k, g = nt*16 + n;
    if (Kg < 73)        w = wih0[g*73 + Kg];
    else if (Kg == 73)  w = bih0[g] + bhh0[g];
    else if (Kg < XK)   w = 0.f;
    else                w = whh0[g*256 + (Kg - XK)];
    off = ((size_t)(nt*NKT0 + kt)*64 + lane)*8 + j;
  } else if (idx < PK0_ELEMS + PK1_ELEMS) {
    int i2 = idx - PK0_ELEMS;
    int nt = i2 / (NKT1*512), rem = i2 % (NKT1*512), kt = rem / 512, li = rem % 512;
    int lane = li >> 3, j = li & 7;
    int n = lane & 15, k = ((lane >> 4) << 3) + j;
    int Kg = kt*32 + k, g = nt*16 + n;
    w = (Kg < 256) ? wih1[g*256 + Kg] : whh1[g*256 + (Kg - 256)];
    off = (size_t)PK0_ELEMS + ((size_t)(nt*NKT1 + kt)*64 + lane)*8 + j;
  } else {
    int i2 = idx - PK0_ELEMS - PK1_ELEMS;
    int nt = i2 / (NKTO*512), rem = i2 % (NKTO*512), kt = rem / 512, li = rem % 512;
    int lane = li >> 3, j = li & 7;
    int n = lane & 15, k = ((lane >> 4) << 3) + j;
    int Kg = kt*32 + k, uh = nt*16 + n;
    w = ow1[uh*256 + Kg];
    off = (size_t)PK0_ELEMS + (size_t)PK1_ELEMS + ((size_t)(nt*NKTO + kt)*64 + lane)*8 + j;
  }
  wsb[off] = f2bf(w);
}

// ---------------- persistent rollout kernel ----------------
// R13 shape (BROWS=64, 3-buffer H, proven epilogues) + R12 mechanism
// (global_load_lds weight ring). Rationale from 18 rounds: VGPR-streamed weights
// saturate the immutable 128-reg cap -> compiler hoists-then-spills -> serialized
// at-use loads + L2 refetch amplification (~50% miss). gload_lds stages weights
// HBM->LDS with ZERO VGPR cost (R12 measured 22% miss, lowest WRITE). Per-wave
// 5-slot ring, groups of 2 gate-tiles, depth-2 counted vmcnt (never 0 mid-pass),
// lgkmcnt(0) slot-reuse guard. vmcnt counts are conservative under spill ops.
__global__ void __launch_bounds__(NTHR)
traj_main(const float* __restrict__ z, const float* __restrict__ cond,
          const float* __restrict__ fiw, const float* __restrict__ fib,
          const float* __restrict__ bih1, const float* __restrict__ bhh1,
          const float* __restrict__ ob1,  const float* __restrict__ ow2,
          const float* __restrict__ ob2,
          const unsigned short* __restrict__ wsb, const int* __restrict__ seqp,
          float* __restrict__ out){
  __shared__ __align__(16) char smem[LDS_TOTAL];
  unsigned short* Xl  = (unsigned short*)(smem + L_X);
  unsigned short* Hl  = (unsigned short*)(smem + L_H);
  float*          OW2l= (float*)(smem + L_OW2);
  float*          OB2l= (float*)(smem + L_OB2);

  const int tid = threadIdx.x, wv = tid >> 6, lane = tid & 63;
  const int bid = blockIdx.x;
  const int row0 = bid * BROWS;
  const int T = *seqp;

  const unsigned short* pk0i = wsb;
  const unsigned short* pk1i = wsb + (size_t)PK0_ELEMS;
  const unsigned short* pkoi = wsb + (size_t)PK0_ELEMS + (size_t)PK1_ELEMS;
  unsigned short* RGu = (unsigned short*)(smem + L_RING) + (size_t)wv*(5*512);

  {
    int r = tid >> 3, seg = tid & 7;
    int gr = row0 + r;
    for (int c = seg*13; c < seg*13 + 13; ++c) {
      float v;
      if (c < 3)        v = cond[gr*6 + c];
      else if (c < 67)  v = z[gr*64 + (c - 3)];
      else if (c < 73)  v = cond[gr*6 + (c - 67)];
      else if (c == 73) v = 1.0f;
      else              v = 0.f;
      Xl[r*XSTR + c] = f2bf(v);
    }
  }
  if (tid < 384) OW2l[tid] = ow2[tid];
  if (tid < 3)   OB2l[tid] = ob2[tid];

  {
    int r = tid >> 3, ub = (tid & 7) * 32;
    int gr = row0 + r;
    #pragma unroll 1
    for (int u = ub; u < ub + 32; ++u) {
      float s0 = fib[u], s1 = fib[256 + u];
      const float* w0r = fiw + (size_t)u * 70;
      const float* w1r = fiw + (size_t)(256 + u) * 70;
      for (int jj = 0; jj < 64; ++jj) { float xv = z[gr*64 + jj]; s0 += xv * w0r[jj]; s1 += xv * w1r[jj]; }
      for (int jj = 0; jj < 6;  ++jj) { float xv = cond[gr*6 + jj]; s0 += xv * w0r[64 + jj]; s1 += xv * w1r[64 + jj]; }
      Hl[0*HBUF + r*HSTR + u] = f2bf(s0);
      Hl[1*HBUF + r*HSTR + u] = f2bf(s1);
    }
  }

  float bias1r[8];
  #pragma unroll
  for (int p = 0; p < 2; ++p) {
    int u = wv*32 + p*16 + (lane & 15);
    #pragma unroll
    for (int g = 0; g < 4; ++g)
      bias1r[p*4 + g] = bih1[g*256 + u] + bhh1[g*256 + u];
  }
  float ob1r = ob1[wv*16 + (lane & 15)];

  float c0s[32], c1s[32];
  #pragma unroll
  for (int i = 0; i < 32; ++i) { c0s[i] = 0.f; c1s[i] = 0.f; }

  __syncthreads();

  const int arow = lane & 15, koff = (lane >> 4) * 8;

  int ia = 0, ib = 1, ic = 2;

  for (int t = 0; t < T; ++t) {
    const unsigned short* Ha = Hl + ia*HBUF;
    const unsigned short* Hb = Hl + ib*HBUF;
    unsigned short*       Hc = Hl + ic*HBUF;
    unsigned short*       HaW= Hl + ia*HBUF;
    unsigned short*       HIDb = Hl + ib*HBUF;   // HID overlays dead h1(t) in M3/M4

    // ===== M1: gates0 (bias in X col 73); h0n -> H[ic] =====
    #pragma unroll
    for (int p = 0; p < 2; ++p) {
      // group n = kt*2 + gpair; tiles = gates {gp*2, gp*2+1}; slots (2n)%5,(2n+1)%5
      #define ISSUE_M1(nn) { \
        constexpr int _kt = (nn) >> 1, _gp = (nn) & 1; \
        stage16(pk0i + ((size_t)(((_gp*2+0)*16 + wv*2 + p)*NKT0 + _kt))*512 + lane*8, \
                RGu + ((2*(nn)  ) % 5)*512); \
        stage16(pk0i + ((size_t)(((_gp*2+1)*16 + wv*2 + p)*NKT0 + _kt))*512 + lane*8, \
                RGu + ((2*(nn)+1) % 5)*512); }
      ISSUE_M1(0); ISSUE_M1(1);

      f32x4 acc[4][4];
      #pragma unroll
      for (int mt = 0; mt < 4; ++mt)
        #pragma unroll
        for (int g = 0; g < 4; ++g) acc[mt][g] = (f32x4){0.f, 0.f, 0.f, 0.f};

      #pragma unroll
      for (int kt = 0; kt < NKT0; ++kt) {
        short8 a[4];
        if (kt < 3) {
          #pragma unroll
          for (int mt = 0; mt < 4; ++mt)
            a[mt] = *(const short8*)(Xl + (mt*16 + arow)*XSTR + kt*32 + koff);
        } else {
          #pragma unroll
          for (int mt = 0; mt < 4; ++mt)
            a[mt] = *(const short8*)(Ha + (mt*16 + arow)*HSTR + (kt - 3)*32 + koff);
        }
        #pragma unroll
        for (int gp = 0; gp < 2; ++gp) {
          const int n = kt*2 + gp;
          if (n < 2*NKT0 - 1) { WAITVM(2) } else { WAITVM(0) }
          short8 w0 = *(const short8*)(RGu + ((2*n  ) % 5)*512 + lane*8);
          short8 w1 = *(const short8*)(RGu + ((2*n+1) % 5)*512 + lane*8);
          #pragma unroll
          for (int mt = 0; mt < 4; ++mt)
            acc[mt][gp*2+0] = __builtin_amdgcn_mfma_f32_16x16x32_bf16(a[mt], w0, acc[mt][gp*2+0], 0, 0, 0);
          #pragma unroll
          for (int mt = 0; mt < 4; ++mt)
            acc[mt][gp*2+1] = __builtin_amdgcn_mfma_f32_16x16x32_bf16(a[mt], w1, acc[mt][gp*2+1], 0, 0, 0);
          if (n + 2 < 2*NKT0) {
            LGKM0;
            const int m = n + 2;
            const int mkt = m >> 1, mgp = m & 1;
            stage16(pk0i + ((size_t)(((mgp*2+0)*16 + wv*2 + p)*NKT0 + mkt))*512 + lane*8,
                    RGu + ((2*m  ) % 5)*512);
            stage16(pk0i + ((size_t)(((mgp*2+1)*16 + wv*2 + p)*NKT0 + mkt))*512 + lane*8,
                    RGu + ((2*m+1) % 5)*512);
          }
        }
      }
      #undef ISSUE_M1

      const int u = wv*32 + p*16 + (lane & 15);
      #pragma unroll
      for (int mt = 0; mt < 4; ++mt) {
        #pragma unroll
        for (int q = 0; q < 4; ++q) {
          float iv = sigm(acc[mt][0][q]);
          float fv = sigm(acc[mt][1][q]);
          float gv = ftanh(acc[mt][2][q]);
          float ov = sigm(acc[mt][3][q]);
          float cn = fv * c0s[(p*4 + mt)*4 + q] + iv * gv;
          c0s[(p*4 + mt)*4 + q] = cn;
          float hn = ov * ftanh(cn);
          int r = mt*16 + ((lane >> 4) << 2) + q;
          Hc[r*HSTR + u] = f2bf(hn);
        }
      }
    }
    __syncthreads();  // B1

    // ===== M2: gates1 (+b); h1n -> H[ia] =====
    #pragma unroll
    for (int p = 0; p < 2; ++p) {
      #define ISSUE_M2(nn) { \
        constexpr int _kt = (nn) >> 1, _gp = (nn) & 1; \
        stage16(pk1i + ((size_t)(((_gp*2+0)*16 + wv*2 + p)*NKT1 + _kt))*512 + lane*8, \
                RGu + ((2*(nn)  ) % 5)*512); \
        stage16(pk1i + ((size_t)(((_gp*2+1)*16 + wv*2 + p)*NKT1 + _kt))*512 + lane*8, \
                RGu + ((2*(nn)+1) % 5)*512); }
      ISSUE_M2(0); ISSUE_M2(1);

      f32x4 acc[4][4];
      #pragma unroll
      for (int mt = 0; mt < 4; ++mt)
        #pragma unroll
        for (int g = 0; g < 4; ++g) {
          float b = bias1r[p*4 + g];
          acc[mt][g] = (f32x4){b, b, b, b};
        }

      #pragma unroll
      for (int kt = 0; kt < NKT1; ++kt) {
        short8 a[4];
        if (kt < 8) {
          #pragma unroll
          for (int mt = 0; mt < 4; ++mt)
            a[mt] = *(const short8*)(Hc + (mt*16 + arow)*HSTR + kt*32 + koff);
        } else {
          #pragma unroll
          for (int mt = 0; mt < 4; ++mt)
            a[mt] = *(const short8*)(Hb + (mt*16 + arow)*HSTR + (kt - 8)*32 + koff);
        }
        #pragma unroll
        for (int gp = 0; gp < 2; ++gp) {
          const int n = kt*2 + gp;
          if (n < 2*NKT1 - 1) { WAITVM(2) } else { WAITVM(0) }
          short8 w0 = *(const short8*)(RGu + ((2*n  ) % 5)*512 + lane*8);
          short8 w1 = *(const short8*)(RGu + ((2*n+1) % 5)*512 + lane*8);
          #pragma unroll
          for (int mt = 0; mt < 4; ++mt)
            acc[mt][gp*2+0] = __builtin_amdgcn_mfma_f32_16x16x32_bf16(a[mt], w0, acc[mt][gp*2+0], 0, 0, 0);
          #pragma unroll
          for (int mt = 0; mt < 4; ++mt)
            acc[mt][gp*2+1] = __builtin_amdgcn_mfma_f32_16x16x32_bf16(a[mt], w1, acc[mt][gp*2+1], 0, 0, 0);
          if (n + 2 < 2*NKT1) {
            LGKM0;
            const int m = n + 2;
            const int mkt = m >> 1, mgp = m & 1;
            stage16(pk1i + ((size_t)(((mgp*2+0)*16 + wv*2 + p)*NKT1 + mkt))*512 + lane*8,
                    RGu + ((2*m  ) % 5)*512);
            stage16(pk1i + ((size_t)(((mgp*2+1)*16 + wv*2 + p)*NKT1 + mkt))*512 + lane*8,
                    RGu + ((2*m+1) % 5)*512);
          }
        }
      }
      #undef ISSUE_M2

      const int u = wv*32 + p*16 + (lane & 15);
      #pragma unroll
      for (int mt = 0; mt < 4; ++mt) {
        #pragma unroll
        for (int q = 0; q < 4; ++q) {
          float iv = sigm(acc[mt][0][q]);
          float fv = sigm(acc[mt][1][q]);
          float gv = ftanh(acc[mt][2][q]);
          float ov = sigm(acc[mt][3][q]);
          float cn = fv * c1s[(p*4 + mt)*4 + q] + iv * gv;
          c1s[(p*4 + mt)*4 + q] = cn;
          float hn = ov * ftanh(cn);
          int r = mt*16 + ((lane >> 4) << 2) + q;
          HaW[r*HSTR + u] = f2bf(hn);
        }
      }
    }
    __syncthreads();  // B2

    // ===== M3: hid = relu(h1n @ out_w1^T + ob1) -> HID bf16 on H[ib] =====
    {
      // single-tile groups, slots n%5, 4 in flight
      #pragma unroll
      for (int s = 0; s < 4; ++s)
        stage16(pkoi + ((size_t)(wv*NKTO + s))*512 + lane*8, RGu + (s % 5)*512);

      f32x4 acc3[4];
      #pragma unroll
      for (int mt = 0; mt < 4; ++mt) acc3[mt] = (f32x4){ob1r, ob1r, ob1r, ob1r};

      #pragma unroll
      for (int kt = 0; kt < NKTO; ++kt) {
        if (kt < 5)      { WAITVM(3) }
        else if (kt == 5){ WAITVM(2) }
        else if (kt == 6){ WAITVM(1) }
        else             { WAITVM(0) }
        const short8 bw = *(const short8*)(RGu + (kt % 5)*512 + lane*8);
        short8 a[4];
        #pragma unroll
        for (int mt = 0; mt < 4; ++mt)
          a[mt] = *(const short8*)(HaW + (mt*16 + arow)*HSTR + kt*32 + koff);
        #pragma unroll
        for (int mt = 0; mt < 4; ++mt)
          acc3[mt] = __builtin_amdgcn_mfma_f32_16x16x32_bf16(a[mt], bw, acc3[mt], 0, 0, 0);
        if (kt + 4 < NKTO) {
          LGKM0;
          stage16(pkoi + ((size_t)(wv*NKTO + kt + 4))*512 + lane*8, RGu + ((kt + 4) % 5)*512);
        }
      }
      const int uh = wv*16 + (lane & 15);
      #pragma unroll
      for (int mt = 0; mt < 4; ++mt)
        #pragma unroll
        for (int q = 0; q < 4; ++q) {
          float hv = fmaxf(acc3[mt][q], 0.f);
          int r = mt*16 + ((lane >> 4) << 2) + q;
          HIDb[r*HID2STR + uh] = f2bf(hv);
        }
    }
    __syncthreads();  // B3

    // ===== M4: out = hid @ out_w2^T + ob2 =====
    {
      int r = tid >> 3, e = tid & 7;
      const unsigned short* hrow = HIDb + r*HID2STR + e*16;
      float s0 = 0.f, s1 = 0.f, s2 = 0.f;
      #pragma unroll
      for (int k = 0; k < 16; ++k) {
        float hv = bf2f(hrow[k]);
        int kk = e*16 + k;
        s0 += hv * OW2l[kk];
        s1 += hv * OW2l[128 + kk];
        s2 += hv * OW2l[256 + kk];
      }
      #pragma unroll
      for (int d = 4; d; d >>= 1) {
        s0 += __shfl_down(s0, d, 8);
        s1 += __shfl_down(s1, d, 8);
        s2 += __shfl_down(s2, d, 8);
      }
      if (e == 0) {
        s0 += OB2l[0]; s1 += OB2l[1]; s2 += OB2l[2];
        int gr = row0 + r;
        float* orow = out + (size_t)gr * (T*3) + t*3;
        orow[0] = s0; orow[1] = s1; orow[2] = s2;
        Xl[r*XSTR + 0] = f2bf(s0);
        Xl[r*XSTR + 1] = f2bf(s1);
        Xl[r*XSTR + 2] = f2bf(s2);
      }
    }
    __syncthreads();  // B4 (drains vmcnt -> clean counts next step)

    int tmp = ia; ia = ic; ic = ib; ib = tmp;
  }
}

extern "C" void kernel_launch(void* const* d_in, const int* in_sizes, int n_in,
                              void* d_out, int out_size, void* d_ws, size_t ws_size,
                              hipStream_t stream){
  const float* z    = (const float*)d_in[0];
  const float* cond = (const float*)d_in[1];
  const float* fiw  = (const float*)d_in[2];
  const float* fib  = (const float*)d_in[3];
  const float* wih0 = (const float*)d_in[4];
  const float* whh0 = (const float*)d_in[5];
  const float* bih0 = (const float*)d_in[6];
  const float* bhh0 = (const float*)d_in[7];
  const float* wih1 = (const float*)d_in[8];
  const float* whh1 = (const float*)d_in[9];
  const float* bih1 = (const float*)d_in[10];
  const float* bhh1 = (const float*)d_in[11];
  const float* ow1  = (const float*)d_in[12];
  const float* ob1  = (const float*)d_in[13];
  const float* ow2  = (const float*)d_in[14];
  const float* ob2  = (const float*)d_in[15];
  const int*   seqp = (const int*)d_in[16];
  unsigned short* wsb = (unsigned short*)d_ws;
  float* outp = (float*)d_out;

  int packtot = PK0_ELEMS + PK1_ELEMS + PKO_ELEMS;
  pack_weights<<<(packtot + 255)/256, 256, 0, stream>>>(wih0, whh0, bih0, bhh0,
                                                        wih1, whh1, ow1, wsb);
  traj_main<<<16384/BROWS, NTHR, 0, stream>>>(z, cond, fiw, fib,
                                              bih1, bhh1,
                                              ob1, ow2, ob2, wsb, seqp, outp);
}

// Round 20
// 5701.648 us; speedup vs baseline: 1.2466x; 1.1474x over previous
//
#include <hip/hip_runtime.h>
#include <hip/hip_bf16.h>

typedef short short8 __attribute__((ext_vector_type(8)));
typedef float f32x4 __attribute__((ext_vector_type(4)));

#define BROWS 64
#define NTHR  512
#define XK    96
#define XSTR  104
#define HSTR  264
#define HIDSTR 129
#define NKT0  11
#define NKT1  16
#define NKTO  8
#define PK0_ELEMS (64*NKT0*512)
#define PK1_ELEMS (64*NKT1*512)
#define PKO_ELEMS (8*NKTO*512)

// LDS layout (bytes) — 149,264 B, STATIC
#define L_X    0
#define L_H    13312
#define HBUF   (BROWS*HSTR)
#define HBUF_B (HBUF*2)
#define L_HID  (L_H + 3*HBUF_B)      // 114688 : [64][129] f32
#define L_OW2  (L_HID + BROWS*HIDSTR*4) // 147712
#define L_OB2  (L_OW2 + 1536)        // 149248
#define LDS_TOTAL 149264

__device__ inline unsigned short f2bf(float x){
  unsigned u = __float_as_uint(x);
  u += 0x7FFFu + ((u >> 16) & 1u);
  return (unsigned short)(u >> 16);
}
__device__ inline float bf2f(unsigned short s){ return __uint_as_float(((unsigned)s) << 16); }
__device__ inline float sigm(float x){ return 1.f / (1.f + __expf(-x)); }
__device__ inline float ftanh(float x){ float e = __expf(2.f*x); return 1.f - 2.f/(e + 1.f); }

// ---------------- weight pre-pack: fp32 -> single bf16, MFMA B-fragment lane order ----
// layout (ushort): region base + ((ntG*NKT + kt)*64 + lane)*8 + j
// B-frag (16x16x32): lane l holds B[k=(l>>4)*8+j][n=l&15], j=0..7
// Layer-0 K-space: [0..2]=cur, [3..66]=z, [67..72]=cond, [73]=BIAS (X col 73 == 1.0),
//                  [74..95]=pad0, [96..351]=w_hh0
__global__ void pack_weights(const float* __restrict__ wih0, const float* __restrict__ whh0,
                             const float* __restrict__ bih0, const float* __restrict__ bhh0,
                             const float* __restrict__ wih1, const float* __restrict__ whh1,
                             const float* __restrict__ ow1,
                             unsigned short* __restrict__ wsb){
  int idx = blockIdx.x * blockDim.x + threadIdx.x;
  int total = PK0_ELEMS + PK1_ELEMS + PKO_ELEMS;
  if (idx >= total) return;
  float w;
  size_t off;
  if (idx < PK0_ELEMS) {
    int nt = idx / (NKT0*512), rem = idx % (NKT0*512), kt = rem / 512, li = rem % 512;
    int lane = li >> 3, j = li & 7;
    int n = lane & 15, k = ((lane >> 4) << 3) + j;
    int Kg = kt*32 + k, g = nt*16 + n;          // g = global gate-unit index [0,1024)
    if (Kg < 73)        w = wih0[g*73 + Kg];
    else if (Kg == 73)  w = bih0[g] + bhh0[g];  // bias via constant-1 input column
    else if (Kg < XK)   w = 0.f;
    else                w = whh0[g*256 + (Kg - XK)];
    off = ((size_t)(nt*NKT0 + kt)*64 + lane)*8 + j;
  } else if (idx < PK0_ELEMS + PK1_ELEMS) {
    int i2 = idx - PK0_ELEMS;
    int nt = i2 / (NKT1*512), rem = i2 % (NKT1*512), kt = rem / 512, li = rem % 512;
    int lane = li >> 3, j = li & 7;
    int n = lane & 15, k = ((lane >> 4) << 3) + j;
    int Kg = kt*32 + k, g = nt*16 + n;
    w = (Kg < 256) ? wih1[g*256 + Kg] : whh1[g*256 + (Kg - 256)];
    off = (size_t)PK0_ELEMS + ((size_t)(nt*NKT1 + kt)*64 + lane)*8 + j;
  } else {
    int i2 = idx - PK0_ELEMS - PK1_ELEMS;
    int nt = i2 / (NKTO*512), rem = i2 % (NKTO*512), kt = rem / 512, li = rem % 512;
    int lane = li >> 3, j = li & 7;
    int n = lane & 15, k = ((lane >> 4) << 3) + j;
    int Kg = kt*32 + k, uh = nt*16 + n;
    w = ow1[uh*256 + Kg];
    off = (size_t)PK0_ELEMS + (size_t)PK1_ELEMS + ((size_t)(nt*NKTO + kt)*64 + lane)*8 + j;
  }
  wsb[off] = f2bf(w);
}

// ---------------- persistent rollout kernel ----------------
// CHAMPION CONFIG (R13, 5721us; reproduced verbatim after R16-R19 perturbations
// all regressed). 19-round ledger: VGPR cap = 65536/NTHR immutable (attributes,
// static LDS, AGPR pins all ignored); bank conflicts (R17), inter-block drift
// (R18), and fetch volume (R19) each individually falsified as the lever.
// The structure below balances compiler-hoisted weight-load concurrency
// (~35 misses in flight/CU) against its unavoidable ~0.5GB spill churn.
__global__ void __launch_bounds__(NTHR)
__attribute__((amdgpu_num_vgpr(256)))
traj_main(const float* __restrict__ z, const float* __restrict__ cond,
          const float* __restrict__ fiw, const float* __restrict__ fib,
          const float* __restrict__ bih1, const float* __restrict__ bhh1,
          const float* __restrict__ ob1,  const float* __restrict__ ow2,
          const float* __restrict__ ob2,
          const unsigned short* __restrict__ wsb, const int* __restrict__ seqp,
          float* __restrict__ out){
  __shared__ __align__(16) char smem[LDS_TOTAL];
  unsigned short* Xl  = (unsigned short*)(smem + L_X);    // [64][104] bf16: cur|z|cond|1|pad
  unsigned short* Hl  = (unsigned short*)(smem + L_H);    // 3 x [64][264] bf16 rotating
  float*          HIDl= (float*)(smem + L_HID);           // [64][129] f32
  float*          OW2l= (float*)(smem + L_OW2);           // [3][128]
  float*          OB2l= (float*)(smem + L_OB2);           // [3]

  const int tid = threadIdx.x, wv = tid >> 6, lane = tid & 63;
  const int bid = blockIdx.x;
  const int row0 = bid * BROWS;
  const int T = *seqp;

  const unsigned short* pk0i = wsb;
  const unsigned short* pk1i = wsb + (size_t)PK0_ELEMS;
  const unsigned short* pkoi = wsb + (size_t)PK0_ELEMS + (size_t)PK1_ELEMS;

  // ---- init: fill X (cur0 = cond[:3], z, cond, 1.0 bias col), copy ow2/ob2 to LDS
  {
    int r = tid >> 3, seg = tid & 7;
    int gr = row0 + r;
    for (int c = seg*13; c < seg*13 + 13; ++c) {
      float v;
      if (c < 3)        v = cond[gr*6 + c];
      else if (c < 67)  v = z[gr*64 + (c - 3)];
      else if (c < 73)  v = cond[gr*6 + (c - 67)];
      else if (c == 73) v = 1.0f;               // bias multiplier column
      else              v = 0.f;
      Xl[r*XSTR + c] = f2bf(v);
    }
  }
  if (tid < 384) OW2l[tid] = ow2[tid];
  if (tid < 3)   OB2l[tid] = ob2[tid];

  // ---- init h0 -> H[0], h1 -> H[1]  (fp32 VALU, one-time)
  {
    int r = tid >> 3, ub = (tid & 7) * 32;
    int gr = row0 + r;
    #pragma unroll 1
    for (int u = ub; u < ub + 32; ++u) {
      float s0 = fib[u], s1 = fib[256 + u];
      const float* w0r = fiw + (size_t)u * 70;
      const float* w1r = fiw + (size_t)(256 + u) * 70;
      for (int jj = 0; jj < 64; ++jj) { float xv = z[gr*64 + jj]; s0 += xv * w0r[jj]; s1 += xv * w1r[jj]; }
      for (int jj = 0; jj < 6;  ++jj) { float xv = cond[gr*6 + jj]; s0 += xv * w0r[64 + jj]; s1 += xv * w1r[64 + jj]; }
      Hl[0*HBUF + r*HSTR + u] = f2bf(s0);
      Hl[1*HBUF + r*HSTR + u] = f2bf(s1);
    }
  }

  // ---- per-lane layer-1 bias preload (layer-0 bias folded into weights)
  float bias1r[8];
  #pragma unroll
  for (int p = 0; p < 2; ++p) {
    int u = wv*32 + p*16 + (lane & 15);
    #pragma unroll
    for (int g = 0; g < 4; ++g)
      bias1r[p*4 + g] = bih1[g*256 + u] + bhh1[g*256 + u];
  }
  float ob1r = ob1[wv*16 + (lane & 15)];

  // ---- c-state in registers (fixed (row,unit)->lane mapping from MFMA C layout)
  float c0s[32], c1s[32];
  #pragma unroll
  for (int i = 0; i < 32; ++i) { c0s[i] = 0.f; c1s[i] = 0.f; }

  __syncthreads();

  const int arow = lane & 15, koff = (lane >> 4) * 8;

  // rotating buffer roles: ia = h0(t), ib = h1(t), ic = free
  int ia = 0, ib = 1, ic = 2;

  for (int t = 0; t < T; ++t) {
    const unsigned short* Ha = Hl + ia*HBUF;  // h0(t)
    const unsigned short* Hb = Hl + ib*HBUF;  // h1(t)
    unsigned short*       Hc = Hl + ic*HBUF;  // free -> h0(t+1)
    unsigned short*       HaW= Hl + ia*HBUF;  // retired after B1 -> h1(t+1)

    // ===== M1: gates0 = [x|1|h0] @ W0^T (bias in col 73), cell 0; h0n -> H[ic] =====
    #pragma unroll
    for (int p = 0; p < 2; ++p) {
      const unsigned short* wb = pk0i + ((size_t)((wv*2 + p)*NKT0)*64 + lane)*8;

      // depth-1 prefetch ring (double buffer)
      short8 wh[2][4];
      #pragma unroll
      for (int g = 0; g < 4; ++g)
        wh[0][g] = *(const short8*)(wb + (size_t)g*(16*NKT0*512));

      f32x4 acc[4][4];
      #pragma unroll
      for (int mt = 0; mt < 4; ++mt)
        #pragma unroll
        for (int g = 0; g < 4; ++g) acc[mt][g] = (f32x4){0.f, 0.f, 0.f, 0.f};

      #pragma unroll
      for (int kt = 0; kt < NKT0; ++kt) {
        const int cb = kt & 1, nb = cb ^ 1;
        if (kt + 1 < NKT0) {
          #pragma unroll
          for (int g = 0; g < 4; ++g)
            wh[nb][g] = *(const short8*)(wb + (size_t)g*(16*NKT0*512) + (size_t)(kt+1)*512);
        }
        short8 a[4];
        if (kt < 3) {
          #pragma unroll
          for (int mt = 0; mt < 4; ++mt)
            a[mt] = *(const short8*)(Xl + (mt*16 + arow)*XSTR + kt*32 + koff);
        } else {
          #pragma unroll
          for (int mt = 0; mt < 4; ++mt)
            a[mt] = *(const short8*)(Ha + (mt*16 + arow)*HSTR + (kt - 3)*32 + koff);
        }
        #pragma unroll
        for (int g = 0; g < 4; ++g)
          #pragma unroll
          for (int mt = 0; mt < 4; ++mt)
            acc[mt][g] = __builtin_amdgcn_mfma_f32_16x16x32_bf16(a[mt], wh[cb][g], acc[mt][g], 0, 0, 0);
      }

      const int u = wv*32 + p*16 + (lane & 15);
      #pragma unroll
      for (int mt = 0; mt < 4; ++mt) {
        #pragma unroll
        for (int q = 0; q < 4; ++q) {
          float iv = sigm(acc[mt][0][q]);
          float fv = sigm(acc[mt][1][q]);
          float gv = ftanh(acc[mt][2][q]);
          float ov = sigm(acc[mt][3][q]);
          float cn = fv * c0s[(p*4 + mt)*4 + q] + iv * gv;
          c0s[(p*4 + mt)*4 + q] = cn;
          float hn = ov * ftanh(cn);
          int r = mt*16 + ((lane >> 4) << 2) + q;
          Hc[r*HSTR + u] = f2bf(hn);
        }
      }
    }
    __syncthreads();  // B1: h0n complete (H[ic]); H[ia] now dead

    // ===== M2: gates1 = [h0n|h1] @ W1^T (+b), cell 1; h1n -> H[ia] (retired) =====
    #pragma unroll
    for (int p = 0; p < 2; ++p) {
      const unsigned short* wb = pk1i + ((size_t)((wv*2 + p)*NKT1)*64 + lane)*8;

      short8 wh[2][4];
      #pragma unroll
      for (int g = 0; g < 4; ++g)
        wh[0][g] = *(const short8*)(wb + (size_t)g*(16*NKT1*512));

      f32x4 acc[4][4];
      #pragma unroll
      for (int mt = 0; mt < 4; ++mt)
        #pragma unroll
        for (int g = 0; g < 4; ++g) {
          float b = bias1r[p*4 + g];
          acc[mt][g] = (f32x4){b, b, b, b};
        }

      #pragma unroll
      for (int kt = 0; kt < NKT1; ++kt) {
        const int cb = kt & 1, nb = cb ^ 1;
        if (kt + 1 < NKT1) {
          #pragma unroll
          for (int g = 0; g < 4; ++g)
            wh[nb][g] = *(const short8*)(wb + (size_t)g*(16*NKT1*512) + (size_t)(kt+1)*512);
        }
        short8 a[4];
        if (kt < 8) {
          #pragma unroll
          for (int mt = 0; mt < 4; ++mt)
            a[mt] = *(const short8*)(Hc + (mt*16 + arow)*HSTR + kt*32 + koff);
        } else {
          #pragma unroll
          for (int mt = 0; mt < 4; ++mt)
            a[mt] = *(const short8*)(Hb + (mt*16 + arow)*HSTR + (kt - 8)*32 + koff);
        }
        #pragma unroll
        for (int g = 0; g < 4; ++g)
          #pragma unroll
          for (int mt = 0; mt < 4; ++mt)
            acc[mt][g] = __builtin_amdgcn_mfma_f32_16x16x32_bf16(a[mt], wh[cb][g], acc[mt][g], 0, 0, 0);
      }

      const int u = wv*32 + p*16 + (lane & 15);
      #pragma unroll
      for (int mt = 0; mt < 4; ++mt) {
        #pragma unroll
        for (int q = 0; q < 4; ++q) {
          float iv = sigm(acc[mt][0][q]);
          float fv = sigm(acc[mt][1][q]);
          float gv = ftanh(acc[mt][2][q]);
          float ov = sigm(acc[mt][3][q]);
          float cn = fv * c1s[(p*4 + mt)*4 + q] + iv * gv;
          c1s[(p*4 + mt)*4 + q] = cn;
          float hn = ov * ftanh(cn);
          int r = mt*16 + ((lane >> 4) << 2) + q;
          HaW[r*HSTR + u] = f2bf(hn);   // retired h0(t) buffer: safe, no wave reads H[ia] now
        }
      }
    }
    __syncthreads();  // B2: h1n visible in H[ia]

    // ===== M3: hid = relu(h1n @ out_w1^T + out_b1) -> LDS fp32 (1 unit-tile per wave) =====
    {
      const unsigned short* wb = pkoi + ((size_t)(wv*NKTO)*64 + lane)*8;
      short8 wh[2];
      wh[0] = *(const short8*)(wb);

      f32x4 acc3[4];
      #pragma unroll
      for (int mt = 0; mt < 4; ++mt) acc3[mt] = (f32x4){ob1r, ob1r, ob1r, ob1r};

      #pragma unroll
      for (int kt = 0; kt < NKTO; ++kt) {
        const int cb = kt & 1, nb = cb ^ 1;
        if (kt + 1 < NKTO)
          wh[nb] = *(const short8*)(wb + (size_t)(kt+1)*512);
        short8 a[4];
        #pragma unroll
        for (int mt = 0; mt < 4; ++mt)
          a[mt] = *(const short8*)(HaW + (mt*16 + arow)*HSTR + kt*32 + koff);
        #pragma unroll
        for (int mt = 0; mt < 4; ++mt)
          acc3[mt] = __builtin_amdgcn_mfma_f32_16x16x32_bf16(a[mt], wh[cb], acc3[mt], 0, 0, 0);
      }
      const int uh = wv*16 + (lane & 15);
      #pragma unroll
      for (int mt = 0; mt < 4; ++mt)
        #pragma unroll
        for (int q = 0; q < 4; ++q) {
          float hv = fmaxf(acc3[mt][q], 0.f);
          int r = mt*16 + ((lane >> 4) << 2) + q;
          HIDl[r*HIDSTR + uh] = hv;
        }
    }
    __syncthreads();  // B3: hid visible

    // ===== M4: out = hid @ out_w2^T + out_b2, all 512 threads:
    // 8 threads per row, 16-wide k-partials, shfl-reduce width 8 =====
    {
      int r = tid >> 3, e = tid & 7;
      const float* hrow = HIDl + r*HIDSTR + e*16;
      float s0 = 0.f, s1 = 0.f, s2 = 0.f;
      #pragma unroll
      for (int k = 0; k < 16; ++k) {
        float hv = hrow[k];
        int kk = e*16 + k;
        s0 += hv * OW2l[kk];
        s1 += hv * OW2l[128 + kk];
        s2 += hv * OW2l[256 + kk];
      }
      #pragma unroll
      for (int d = 4; d; d >>= 1) {
        s0 += __shfl_down(s0, d, 8);
        s1 += __shfl_down(s1, d, 8);
        s2 += __shfl_down(s2, d, 8);
      }
      if (e == 0) {
        s0 += OB2l[0]; s1 += OB2l[1]; s2 += OB2l[2];
        int gr = row0 + r;
        float* orow = out + (size_t)gr * (T*3) + t*3;
        orow[0] = s0; orow[1] = s1; orow[2] = s2;
        Xl[r*XSTR + 0] = f2bf(s0);
        Xl[r*XSTR + 1] = f2bf(s1);
        Xl[r*XSTR + 2] = f2bf(s2);
      }
    }
    __syncthreads();  // B4: cur visible, hid reads done

    // rotate roles: h0(t+1) in old ic; h1(t+1) in old ia; old ib freed
    int tmp = ia; ia = ic; ic = ib; ib = tmp;
  }
}

extern "C" void kernel_launch(void* const* d_in, const int* in_sizes, int n_in,
                              void* d_out, int out_size, void* d_ws, size_t ws_size,
                              hipStream_t stream){
  const float* z    = (const float*)d_in[0];
  const float* cond = (const float*)d_in[1];
  const float* fiw  = (const float*)d_in[2];
  const float* fib  = (const float*)d_in[3];
  const float* wih0 = (const float*)d_in[4];
  const float* whh0 = (const float*)d_in[5];
  const float* bih0 = (const float*)d_in[6];
  const float* bhh0 = (const float*)d_in[7];
  const float* wih1 = (const float*)d_in[8];
  const float* whh1 = (const float*)d_in[9];
  const float* bih1 = (const float*)d_in[10];
  const float* bhh1 = (const float*)d_in[11];
  const float* ow1  = (const float*)d_in[12];
  const float* ob1  = (const float*)d_in[13];
  const float* ow2  = (const float*)d_in[14];
  const float* ob2  = (const float*)d_in[15];
  const int*   seqp = (const int*)d_in[16];
  unsigned short* wsb = (unsigned short*)d_ws;
  float* outp = (float*)d_out;

  int packtot = PK0_ELEMS + PK1_ELEMS + PKO_ELEMS;
  pack_weights<<<(packtot + 255)/256, 256, 0, stream>>>(wih0, whh0, bih0, bhh0,
                                                        wih1, whh1, ow1, wsb);
  traj_main<<<16384/BROWS, NTHR, 0, stream>>>(z, cond, fiw, fib,
                                              bih1, bhh1,
                                              ob1, ow2, ob2, wsb, seqp, outp);
}